// Round 2
// baseline (1088.003 us; speedup 1.0000x reference)
//
#include <hip/hip_runtime.h>
#include <hip/hip_bf16.h>
#include <float.h>
#include <math.h>

// Problem shapes (fixed per setup_inputs)
#define NB     8
#define N_PC   20000
#define NS     2048
#define KPTS   16384
#define D_IN   768
#define C_OUT  256
#define KSPLIT 16
#define SPT    4      // seeds per thread in k2
#define NTILE  64     // seed columns per k4 block

// ---------------- ws layout (float offsets) ----------------
#define WS_STATS 0
#define WS_WTP   32
#define WS_WT1   (WS_WTP + 768*256)
#define WS_WT2   (WS_WT1 + 256*256)
#define WS_PD    (WS_WT2 + 256*256)
#define WS_PI    (WS_PD + NB*KSPLIT*NS)
#define WS_IDX   (WS_PI + NB*KSPLIT*NS)
#define WS_G     (WS_IDX + NB*NS)
// total ~13.45M floats ~= 54 MB

// K0: transpose weights, zero the loss accumulator slot of d_out
__global__ void k0_prep(const float* __restrict__ Wp, const float* __restrict__ Wa1,
                        const float* __restrict__ Wa2,
                        float* __restrict__ wtp, float* __restrict__ wt1,
                        float* __restrict__ wt2, float* __restrict__ loss_slot) {
    int t = blockIdx.x * 256 + threadIdx.x;
    if (t == 0) *loss_slot = 0.f;
    if (t < 256 * 768) {                 // W_proj [256][768] -> [768][256]
        int o = t / 768, d = t % 768;
        wtp[d * 256 + o] = Wp[t];
    }
    int t2 = t - 256 * 768;
    if (t2 >= 0 && t2 < 256 * 256) {     // W_a1 [256][256] -> T
        int o = t2 / 256, c = t2 % 256;
        wt1[c * 256 + o] = Wa1[t2];
    }
    int t3 = t2 - 256 * 256;
    if (t3 >= 0 && t3 < 256 * 256) {     // W_a2
        int o = t3 / 256, c = t3 % 256;
        wt2[c * 256 + o] = Wa2[t3];
    }
}

// K1: per-batch centroid + max-radius scale
__global__ void k1_stats(const float* __restrict__ pc, float* __restrict__ stats) {
    int b = blockIdx.x, t = threadIdx.x;
    __shared__ float rx[256], ry[256], rz[256];
    __shared__ float c3[3];
    const float* p = pc + (size_t)b * N_PC * 3;
    float sx = 0.f, sy = 0.f, sz = 0.f;
    for (int i = t; i < N_PC; i += 256) {
        sx += p[3 * i]; sy += p[3 * i + 1]; sz += p[3 * i + 2];
    }
    rx[t] = sx; ry[t] = sy; rz[t] = sz;
    __syncthreads();
    for (int s = 128; s > 0; s >>= 1) {
        if (t < s) { rx[t] += rx[t + s]; ry[t] += ry[t + s]; rz[t] += rz[t + s]; }
        __syncthreads();
    }
    if (t == 0) {
        c3[0] = rx[0] / 20000.f; c3[1] = ry[0] / 20000.f; c3[2] = rz[0] / 20000.f;
    }
    __syncthreads();
    float cx = c3[0], cy = c3[1], cz = c3[2];
    float mx = 0.f;
    for (int i = t; i < N_PC; i += 256) {
        float dx = p[3 * i] - cx, dy = p[3 * i + 1] - cy, dz = p[3 * i + 2] - cz;
        mx = fmaxf(mx, dx * dx + dy * dy + dz * dz);
    }
    rx[t] = mx;
    __syncthreads();
    for (int s = 128; s > 0; s >>= 1) {
        if (t < s) rx[t] = fmaxf(rx[t], rx[t + s]);
        __syncthreads();
    }
    if (t == 0) {
        stats[b * 4 + 0] = cx; stats[b * 4 + 1] = cy; stats[b * 4 + 2] = cz;
        stats[b * 4 + 3] = sqrtf(rx[0]);   // sqrt(max(sq)) == max(norm) (monotone, exact-rounded)
    }
}

// K2: 1-NN partial argmin. SPT seeds/thread so each LDS point read feeds SPT
// distance computations (round-0 was ds_read-issue-bound). KSPLIT=16 -> 256 blocks.
__global__ void k2_nn(const float* __restrict__ seed, const float* __restrict__ pts,
                      const float* __restrict__ stats,
                      float* __restrict__ pd, int* __restrict__ pi) {
    int tile = blockIdx.x, split = blockIdx.y, b = blockIdx.z, t = threadIdx.x;
    float cx = stats[b * 4], cy = stats[b * 4 + 1], cz = stats[b * 4 + 2], sc = stats[b * 4 + 3];

    float sx[SPT], sy[SPT], sz[SPT], ssv[SPT];
    float best[SPT];
    int   bi[SPT];
    #pragma unroll
    for (int i = 0; i < SPT; i++) {
        int n = tile * (256 * SPT) + i * 256 + t;
        const float* s3 = seed + ((size_t)b * NS + n) * 3;
        sx[i] = (s3[0] - cx) / sc;
        sy[i] = (s3[1] - cy) / sc;
        sz[i] = (s3[2] - cz) / sc;
        ssv[i] = fmaf(sz[i], sz[i], fmaf(sy[i], sy[i], sx[i] * sx[i]));
        best[i] = FLT_MAX;
        bi[i] = 0;
    }

    __shared__ float4 lp[256];
    const int kbeg = split * (KPTS / KSPLIT);          // 1024 points per split
    for (int kc = kbeg; kc < kbeg + KPTS / KSPLIT; kc += 256) {
        const float* p3 = pts + ((size_t)b * KPTS + kc + t) * 3;
        float px = (p3[0] - cx) / sc, py = (p3[1] - cy) / sc, pz = (p3[2] - cz) / sc;
        lp[t] = make_float4(px, py, pz, fmaf(pz, pz, fmaf(py, py, px * px)));
        __syncthreads();
        #pragma unroll 4
        for (int j = 0; j < 256; j++) {
            float4 q = lp[j];
            int cand = kc + j;
            #pragma unroll
            for (int i = 0; i < SPT; i++) {
                float dot = fmaf(sz[i], q.z, fmaf(sy[i], q.y, sx[i] * q.x));
                float d = (ssv[i] + q.w) - 2.f * dot;
                bool m = d < best[i];
                best[i] = m ? d : best[i];
                bi[i]   = m ? cand : bi[i];
            }
        }
        __syncthreads();
    }
    #pragma unroll
    for (int i = 0; i < SPT; i++) {
        int n = tile * (256 * SPT) + i * 256 + t;
        pd[((size_t)b * KSPLIT + split) * NS + n] = best[i];
        pi[((size_t)b * KSPLIT + split) * NS + n] = bi[i];
    }
}

// K2b: merge K-split partials (split ascending => lowest-k wins ties via strict <)
__global__ void k2b_merge(const float* __restrict__ pd, const int* __restrict__ pi,
                          int* __restrict__ idx) {
    int g = blockIdx.x * 256 + threadIdx.x;   // 0 .. 16383
    int b = g >> 11, n = g & 2047;
    float best = FLT_MAX;
    int bi = 0;
    for (int s = 0; s < KSPLIT; s++) {
        float d = pd[((size_t)b * KSPLIT + s) * NS + n];
        int i = pi[((size_t)b * KSPLIT + s) * NS + n];
        if (d < best) { best = d; bi = i; }
    }
    idx[b * NS + n] = bi;
}

// K3: gather G[b][d][n] = feat[b][d][idx[b][n]]  (row-wise: one block per (b,d))
__global__ void k3_gather(const float* __restrict__ feat, const int* __restrict__ idx,
                          float* __restrict__ G) {
    int bd = blockIdx.x;
    int b = bd / D_IN;
    const float* frow = feat + (size_t)bd * KPTS;
    const int* ib = idx + b * NS;
    float* grow = G + (size_t)bd * NS;
    for (int n = threadIdx.x; n < NS; n += 256)
        grow[n] = frow[ib[n]];
}

// K4: fused proj(768->256) + LayerNorm(C) + adapter + loss.
// 2D register-tile GEMM: thread owns 8o x 8n of the 256x64 output tile.
// Per c: 2 LDS b128 (X) + 4 global b128 (W or G) + 64 FMA — FMA-bound by design.
__launch_bounds__(256, 1)
__global__ void k4_fused(const float* __restrict__ G,
                         const float* __restrict__ wtp, const float* __restrict__ wt1,
                         const float* __restrict__ wt2,
                         const float* __restrict__ bp, const float* __restrict__ b1v,
                         const float* __restrict__ b2v,
                         const float* __restrict__ ft,
                         float* __restrict__ out, float* __restrict__ loss) {
    int blk = blockIdx.x;
    int b = blk >> 5, tile = blk & 31;
    int t = threadIdx.x;
    int o0 = (t >> 3) * 8;      // 32 o-groups of 8
    int n0 = (t & 7) * 8;       // 8  n-groups of 8

    __shared__ float tA[256 * NTILE];   // 64 KB: x, then x_ln  [row=c][col=n]
    __shared__ float tB[256 * NTILE];   // 64 KB: h
    __shared__ float red[256];
    __shared__ float mu_s[NTILE], rv_s[NTILE];
    __shared__ float lred[4];

    float acc[8][8];
    #pragma unroll
    for (int i = 0; i < 8; i++)
        #pragma unroll
        for (int j = 0; j < 8; j++) acc[i][j] = 0.f;

    // ---- phase A: x = W_proj @ G  (G read directly from global, per-lane)
    const float* Gb = G + ((size_t)b * D_IN) * NS + tile * NTILE;
    #pragma unroll 2
    for (int c = 0; c < D_IN; c++) {
        float4 w0 = *reinterpret_cast<const float4*>(wtp + c * 256 + o0);
        float4 w1 = *reinterpret_cast<const float4*>(wtp + c * 256 + o0 + 4);
        float4 g0 = *reinterpret_cast<const float4*>(Gb + (size_t)c * NS + n0);
        float4 g1 = *reinterpret_cast<const float4*>(Gb + (size_t)c * NS + n0 + 4);
        float wv[8] = {w0.x, w0.y, w0.z, w0.w, w1.x, w1.y, w1.z, w1.w};
        float gv[8] = {g0.x, g0.y, g0.z, g0.w, g1.x, g1.y, g1.z, g1.w};
        #pragma unroll
        for (int i = 0; i < 8; i++)
            #pragma unroll
            for (int j = 0; j < 8; j++)
                acc[i][j] = fmaf(wv[i], gv[j], acc[i][j]);
    }
    {
        float4 ba = *reinterpret_cast<const float4*>(bp + o0);
        float4 bb = *reinterpret_cast<const float4*>(bp + o0 + 4);
        float bv[8] = {ba.x, ba.y, ba.z, ba.w, bb.x, bb.y, bb.z, bb.w};
        #pragma unroll
        for (int i = 0; i < 8; i++)
            #pragma unroll
            for (int j = 0; j < 8; j++)
                tA[(o0 + i) * NTILE + n0 + j] = acc[i][j] + bv[i];
    }
    __syncthreads();

    // ---- LayerNorm over channels, column-major access (stride-1 across lanes)
    {
        int q = t >> 6, n = t & 63;      // 4 row-groups x 64 columns
        float s = 0.f;
        #pragma unroll 16
        for (int r = 0; r < 64; r++) s += tA[(q * 64 + r) * NTILE + n];
        red[t] = s;
        __syncthreads();
        if (q == 0)
            mu_s[n] = (red[n] + red[64 + n] + red[128 + n] + red[192 + n]) * (1.f / 256.f);
        __syncthreads();
        float mu = mu_s[n];
        float v = 0.f;
        #pragma unroll 16
        for (int r = 0; r < 64; r++) {
            float x = tA[(q * 64 + r) * NTILE + n] - mu;
            v = fmaf(x, x, v);
        }
        red[t] = v;
        __syncthreads();
        if (q == 0) {
            float var = (red[n] + red[64 + n] + red[128 + n] + red[192 + n]) * (1.f / 256.f);
            rv_s[n] = rsqrtf(var + 1e-5f);
        }
        __syncthreads();
        float rv = rv_s[n];
        #pragma unroll 16
        for (int r = 0; r < 64; r++) {
            int row = q * 64 + r;
            tA[row * NTILE + n] = (tA[row * NTILE + n] - mu) * rv;
        }
    }
    __syncthreads();

    // ---- phase B: h = relu(W_a1 @ x_ln + b1)
    #pragma unroll
    for (int i = 0; i < 8; i++)
        #pragma unroll
        for (int j = 0; j < 8; j++) acc[i][j] = 0.f;
    #pragma unroll 2
    for (int c = 0; c < 256; c++) {
        float4 w0 = *reinterpret_cast<const float4*>(wt1 + c * 256 + o0);
        float4 w1 = *reinterpret_cast<const float4*>(wt1 + c * 256 + o0 + 4);
        float4 x0 = *reinterpret_cast<const float4*>(&tA[c * NTILE + n0]);
        float4 x1 = *reinterpret_cast<const float4*>(&tA[c * NTILE + n0 + 4]);
        float wv[8] = {w0.x, w0.y, w0.z, w0.w, w1.x, w1.y, w1.z, w1.w};
        float xv[8] = {x0.x, x0.y, x0.z, x0.w, x1.x, x1.y, x1.z, x1.w};
        #pragma unroll
        for (int i = 0; i < 8; i++)
            #pragma unroll
            for (int j = 0; j < 8; j++)
                acc[i][j] = fmaf(wv[i], xv[j], acc[i][j]);
    }
    {
        float4 ba = *reinterpret_cast<const float4*>(b1v + o0);
        float4 bb = *reinterpret_cast<const float4*>(b1v + o0 + 4);
        float bv[8] = {ba.x, ba.y, ba.z, ba.w, bb.x, bb.y, bb.z, bb.w};
        #pragma unroll
        for (int i = 0; i < 8; i++)
            #pragma unroll
            for (int j = 0; j < 8; j++)
                tB[(o0 + i) * NTILE + n0 + j] = fmaxf(acc[i][j] + bv[i], 0.f);
    }
    __syncthreads();

    // ---- phase C: f = W_a2 @ h + b2 ; write out; loss partial
    #pragma unroll
    for (int i = 0; i < 8; i++)
        #pragma unroll
        for (int j = 0; j < 8; j++) acc[i][j] = 0.f;
    #pragma unroll 2
    for (int c = 0; c < 256; c++) {
        float4 w0 = *reinterpret_cast<const float4*>(wt2 + c * 256 + o0);
        float4 w1 = *reinterpret_cast<const float4*>(wt2 + c * 256 + o0 + 4);
        float4 h0 = *reinterpret_cast<const float4*>(&tB[c * NTILE + n0]);
        float4 h1 = *reinterpret_cast<const float4*>(&tB[c * NTILE + n0 + 4]);
        float wv[8] = {w0.x, w0.y, w0.z, w0.w, w1.x, w1.y, w1.z, w1.w};
        float hv[8] = {h0.x, h0.y, h0.z, h0.w, h1.x, h1.y, h1.z, h1.w};
        #pragma unroll
        for (int i = 0; i < 8; i++)
            #pragma unroll
            for (int j = 0; j < 8; j++)
                acc[i][j] = fmaf(wv[i], hv[j], acc[i][j]);
    }
    {
        float4 ba = *reinterpret_cast<const float4*>(b2v + o0);
        float4 bb = *reinterpret_cast<const float4*>(b2v + o0 + 4);
        float bv[8] = {ba.x, ba.y, ba.z, ba.w, bb.x, bb.y, bb.z, bb.w};
        const float* ftb = ft + ((size_t)b * 256) * NS + tile * NTILE;
        float* ob = out + ((size_t)b * 256) * NS + tile * NTILE;
        float ls = 0.f;
        #pragma unroll
        for (int i = 0; i < 8; i++) {
            int row = o0 + i;
            float4 f0, f1;
            f0.x = acc[i][0] + bv[i]; f0.y = acc[i][1] + bv[i];
            f0.z = acc[i][2] + bv[i]; f0.w = acc[i][3] + bv[i];
            f1.x = acc[i][4] + bv[i]; f1.y = acc[i][5] + bv[i];
            f1.z = acc[i][6] + bv[i]; f1.w = acc[i][7] + bv[i];
            *reinterpret_cast<float4*>(ob + (size_t)row * NS + n0)     = f0;
            *reinterpret_cast<float4*>(ob + (size_t)row * NS + n0 + 4) = f1;
            float4 t0 = *reinterpret_cast<const float4*>(ftb + (size_t)row * NS + n0);
            float4 t1 = *reinterpret_cast<const float4*>(ftb + (size_t)row * NS + n0 + 4);
            float d0 = f0.x - t0.x, d1 = f0.y - t0.y, d2 = f0.z - t0.z, d3 = f0.w - t0.w;
            float d4 = f1.x - t1.x, d5 = f1.y - t1.y, d6 = f1.z - t1.z, d7 = f1.w - t1.w;
            ls = fmaf(d0, d0, ls); ls = fmaf(d1, d1, ls);
            ls = fmaf(d2, d2, ls); ls = fmaf(d3, d3, ls);
            ls = fmaf(d4, d4, ls); ls = fmaf(d5, d5, ls);
            ls = fmaf(d6, d6, ls); ls = fmaf(d7, d7, ls);
        }
        for (int off = 32; off > 0; off >>= 1) ls += __shfl_down(ls, off);
        if ((t & 63) == 0) lred[t >> 6] = ls;
        __syncthreads();
        if (t == 0) {
            float tot = lred[0] + lred[1] + lred[2] + lred[3];
            atomicAdd(loss, tot * (1.f / 4194304.f));
        }
    }
}

extern "C" void kernel_launch(void* const* d_in, const int* in_sizes, int n_in,
                              void* d_out, int out_size, void* d_ws, size_t ws_size,
                              hipStream_t stream) {
    const float* pc   = (const float*)d_in[0];
    const float* seed = (const float*)d_in[1];
    const float* pts  = (const float*)d_in[2];
    const float* feat = (const float*)d_in[3];
    const float* ft   = (const float*)d_in[4];
    const float* Wp   = (const float*)d_in[5];
    const float* bp   = (const float*)d_in[6];
    const float* Wa1  = (const float*)d_in[7];
    const float* b1v  = (const float*)d_in[8];
    const float* Wa2  = (const float*)d_in[9];
    const float* b2v  = (const float*)d_in[10];

    float* out  = (float*)d_out;                       // [8][256][2048] + 1 loss
    float* ws   = (float*)d_ws;
    float* stats = ws + WS_STATS;
    float* wtp   = ws + WS_WTP;
    float* wt1   = ws + WS_WT1;
    float* wt2   = ws + WS_WT2;
    float* pd    = ws + WS_PD;
    int*   pi    = (int*)(ws + WS_PI);
    int*   idx   = (int*)(ws + WS_IDX);
    float* G     = ws + WS_G;
    float* loss_slot = out + (size_t)NB * C_OUT * NS;  // index 4194304

    k0_prep<<<(256 * 768 + 2 * 256 * 256 + 255) / 256, 256, 0, stream>>>(
        Wp, Wa1, Wa2, wtp, wt1, wt2, loss_slot);
    k1_stats<<<NB, 256, 0, stream>>>(pc, stats);
    k2_nn<<<dim3(NS / (256 * SPT), KSPLIT, NB), 256, 0, stream>>>(seed, pts, stats, pd, pi);
    k2b_merge<<<(NB * NS) / 256, 256, 0, stream>>>(pd, pi, idx);
    k3_gather<<<NB * D_IN, 256, 0, stream>>>(feat, idx, G);
    k4_fused<<<NB * (NS / NTILE), 256, 0, stream>>>(
        G, wtp, wt1, wt2, bp, b1v, b2v, ft, out, loss_slot);
}

// Round 3
// 823.284 us; speedup vs baseline: 1.3215x; 1.3215x over previous
//
#include <hip/hip_runtime.h>
#include <hip/hip_bf16.h>
#include <float.h>
#include <math.h>

// Problem shapes (fixed per setup_inputs)
#define NB     8
#define N_PC   20000
#define NS     2048
#define KPTS   16384
#define D_IN   768
#define C_OUT  256
#define KSPLIT 32
#define SPT    4

typedef __attribute__((ext_vector_type(8))) short  short8v;   // 8 bf16 = 4 VGPR (MFMA A/B frag)
typedef __attribute__((ext_vector_type(8))) unsigned short ushort8v;
typedef __attribute__((ext_vector_type(4))) float  f32x4;     // MFMA C/D frag

#define MFMA(a,b,c) __builtin_amdgcn_mfma_f32_16x16x32_bf16((a),(b),(c),0,0,0)

// ---------------- ws layout (float units) ----------------
#define OFF_STATS 0
#define OFF_WPH   32
#define OFF_WPL   (OFF_WPH + 98304)      // 256*768 ushort = 98304 f
#define OFF_W1H   (OFF_WPL + 98304)
#define OFF_W1L   (OFF_W1H + 32768)      // 256*256 ushort = 32768 f
#define OFF_W2H   (OFF_W1L + 32768)
#define OFF_W2L   (OFF_W2H + 32768)
#define OFF_PD    (OFF_W2L + 32768)
#define OFF_PI    (OFF_PD + NB*KSPLIT*NS)
#define OFF_IDX   (OFF_PI + NB*KSPLIT*NS)
#define OFF_GTH   (OFF_IDX + NB*NS)      // 16384*768 ushort = 6291456 f
#define OFF_GTL   (OFF_GTH + 6291456)
#define OFF_G     (OFF_GTL + 6291456)    // 12582912 f ; reused for Xt/Ht after k3b
#define OFF_XTH   OFF_G                  // 16384*256 ushort = 2097152 f
#define OFF_XTL   (OFF_XTH + 2097152)
#define OFF_HTH   (OFF_XTL + 2097152)
#define OFF_HTL   (OFF_HTH + 2097152)

// ---- bf16 split helpers (RNE, matches __float2bfloat16) ----
__device__ __forceinline__ unsigned short f2bf(float x) {
    unsigned u = __float_as_uint(x);
    unsigned r = (u + 0x7FFFu + ((u >> 16) & 1u)) >> 16;
    return (unsigned short)r;
}
__device__ __forceinline__ float bf2f(unsigned short b) {
    return __uint_as_float(((unsigned)b) << 16);
}

// K0: weights -> hi/lo bf16 (layout preserved: [o][k] row-major = MFMA A layout); zero loss
__global__ void k0_prep(const float* __restrict__ Wp, const float* __restrict__ W1,
                        const float* __restrict__ W2,
                        unsigned short* __restrict__ wph, unsigned short* __restrict__ wpl,
                        unsigned short* __restrict__ w1h, unsigned short* __restrict__ w1l,
                        unsigned short* __restrict__ w2h, unsigned short* __restrict__ w2l,
                        float* __restrict__ loss_slot) {
    int t = blockIdx.x * 256 + threadIdx.x;
    if (t == 0) *loss_slot = 0.f;
    if (t < 196608) {
        float x = Wp[t]; unsigned short h = f2bf(x);
        wph[t] = h; wpl[t] = f2bf(x - bf2f(h));
    } else if (t < 262144) {
        int i = t - 196608;
        float x = W1[i]; unsigned short h = f2bf(x);
        w1h[i] = h; w1l[i] = f2bf(x - bf2f(h));
    } else if (t < 327680) {
        int i = t - 262144;
        float x = W2[i]; unsigned short h = f2bf(x);
        w2h[i] = h; w2l[i] = f2bf(x - bf2f(h));
    }
}

// K1: per-batch centroid + max-radius scale (1024 threads)
__global__ void k1_stats(const float* __restrict__ pc, float* __restrict__ stats) {
    int b = blockIdx.x, t = threadIdx.x;
    __shared__ float rx[1024], ry[1024], rz[1024];
    __shared__ float c3[3];
    const float* p = pc + (size_t)b * N_PC * 3;
    float sx = 0.f, sy = 0.f, sz = 0.f;
    for (int i = t; i < N_PC; i += 1024) {
        sx += p[3 * i]; sy += p[3 * i + 1]; sz += p[3 * i + 2];
    }
    rx[t] = sx; ry[t] = sy; rz[t] = sz;
    __syncthreads();
    for (int s = 512; s > 0; s >>= 1) {
        if (t < s) { rx[t] += rx[t + s]; ry[t] += ry[t + s]; rz[t] += rz[t + s]; }
        __syncthreads();
    }
    if (t == 0) {
        c3[0] = rx[0] / 20000.f; c3[1] = ry[0] / 20000.f; c3[2] = rz[0] / 20000.f;
    }
    __syncthreads();
    float cx = c3[0], cy = c3[1], cz = c3[2];
    float mx = 0.f;
    for (int i = t; i < N_PC; i += 1024) {
        float dx = p[3 * i] - cx, dy = p[3 * i + 1] - cy, dz = p[3 * i + 2] - cz;
        mx = fmaxf(mx, dx * dx + dy * dy + dz * dz);
    }
    rx[t] = mx;
    __syncthreads();
    for (int s = 512; s > 0; s >>= 1) {
        if (t < s) rx[t] = fmaxf(rx[t], rx[t + s]);
        __syncthreads();
    }
    if (t == 0) {
        stats[b * 4 + 0] = cx; stats[b * 4 + 1] = cy; stats[b * 4 + 2] = cz;
        stats[b * 4 + 3] = sqrtf(rx[0]);
    }
}

// K2: 1-NN partial argmin, KSPLIT=32 -> 512 blocks (2/CU)
__global__ void k2_nn(const float* __restrict__ seed, const float* __restrict__ pts,
                      const float* __restrict__ stats,
                      float* __restrict__ pd, int* __restrict__ pi) {
    int tile = blockIdx.x, split = blockIdx.y, b = blockIdx.z, t = threadIdx.x;
    float cx = stats[b * 4], cy = stats[b * 4 + 1], cz = stats[b * 4 + 2], sc = stats[b * 4 + 3];

    float sx[SPT], sy[SPT], sz[SPT], ssv[SPT];
    float best[SPT];
    int   bi[SPT];
    #pragma unroll
    for (int i = 0; i < SPT; i++) {
        int n = tile * (256 * SPT) + i * 256 + t;
        const float* s3 = seed + ((size_t)b * NS + n) * 3;
        sx[i] = (s3[0] - cx) / sc;
        sy[i] = (s3[1] - cy) / sc;
        sz[i] = (s3[2] - cz) / sc;
        ssv[i] = fmaf(sz[i], sz[i], fmaf(sy[i], sy[i], sx[i] * sx[i]));
        best[i] = FLT_MAX;
        bi[i] = 0;
    }

    __shared__ float4 lp[256];
    const int kbeg = split * (KPTS / KSPLIT);          // 512 points per split
    for (int kc = kbeg; kc < kbeg + KPTS / KSPLIT; kc += 256) {
        const float* p3 = pts + ((size_t)b * KPTS + kc + t) * 3;
        float px = (p3[0] - cx) / sc, py = (p3[1] - cy) / sc, pz = (p3[2] - cz) / sc;
        lp[t] = make_float4(px, py, pz, fmaf(pz, pz, fmaf(py, py, px * px)));
        __syncthreads();
        #pragma unroll 4
        for (int j = 0; j < 256; j++) {
            float4 q = lp[j];
            int cand = kc + j;
            #pragma unroll
            for (int i = 0; i < SPT; i++) {
                float dot = fmaf(sz[i], q.z, fmaf(sy[i], q.y, sx[i] * q.x));
                float d = (ssv[i] + q.w) - 2.f * dot;
                bool m = d < best[i];
                best[i] = m ? d : best[i];
                bi[i]   = m ? cand : bi[i];
            }
        }
        __syncthreads();
    }
    #pragma unroll
    for (int i = 0; i < SPT; i++) {
        int n = tile * (256 * SPT) + i * 256 + t;
        pd[((size_t)b * KSPLIT + split) * NS + n] = best[i];
        pi[((size_t)b * KSPLIT + split) * NS + n] = bi[i];
    }
}

// K2b: merge K-split partials (split ascending => lowest-k wins ties via strict <)
__global__ void k2b_merge(const float* __restrict__ pd, const int* __restrict__ pi,
                          int* __restrict__ idx) {
    int g = blockIdx.x * 256 + threadIdx.x;
    int b = g >> 11, n = g & 2047;
    float best = FLT_MAX;
    int bi = 0;
    for (int s = 0; s < KSPLIT; s++) {
        float d = pd[((size_t)b * KSPLIT + s) * NS + n];
        int i = pi[((size_t)b * KSPLIT + s) * NS + n];
        if (d < best) { best = d; bi = i; }
    }
    idx[b * NS + n] = bi;
}

// K3: gather G[b][d][n] = feat[b][d][idx[b][n]]  (row-wise: one block per (b,d))
__global__ void k3_gather(const float* __restrict__ feat, const int* __restrict__ idx,
                          float* __restrict__ G) {
    int bd = blockIdx.x;
    int b = bd / D_IN;
    const float* frow = feat + (size_t)bd * KPTS;
    const int* ib = idx + b * NS;
    float* grow = G + (size_t)bd * NS;
    for (int n = threadIdx.x; n < NS; n += 256)
        grow[n] = frow[ib[n]];
}

// K3b: transpose+split G[b][d][n] f32 -> Gt_hi/Gt_lo [bn][768] bf16 (k-contiguous B layout)
__global__ __launch_bounds__(256) void k3b_tr(const float* __restrict__ G,
                                              unsigned short* __restrict__ gth,
                                              unsigned short* __restrict__ gtl) {
    int d0 = blockIdx.x * 64, bn0 = blockIdx.y * 64;
    int b = bn0 >> 11, nb = bn0 & 2047;
    __shared__ float ld[64][65];
    int t = threadIdx.x;
    int rr = t >> 2, cc = (t & 3) * 16;
    const float* gp = G + ((size_t)(b * D_IN + d0 + rr)) * NS + nb + cc;
    #pragma unroll
    for (int i = 0; i < 4; i++) {
        float4 v = *reinterpret_cast<const float4*>(gp + i * 4);
        ld[rr][cc + i * 4 + 0] = v.x; ld[rr][cc + i * 4 + 1] = v.y;
        ld[rr][cc + i * 4 + 2] = v.z; ld[rr][cc + i * 4 + 3] = v.w;
    }
    __syncthreads();
    int nl = t >> 2, dg = (t & 3) * 16;
    ushort8v h1, h2, l1, l2;
    #pragma unroll
    for (int i = 0; i < 8; i++) {
        float v = ld[dg + i][nl];
        unsigned short h = f2bf(v);
        h1[i] = h; l1[i] = f2bf(v - bf2f(h));
    }
    #pragma unroll
    for (int i = 0; i < 8; i++) {
        float v = ld[dg + 8 + i][nl];
        unsigned short h = f2bf(v);
        h2[i] = h; l2[i] = f2bf(v - bf2f(h));
    }
    size_t rb = ((size_t)(bn0 + nl)) * D_IN + d0 + dg;
    *reinterpret_cast<ushort8v*>(gth + rb)     = h1;
    *reinterpret_cast<ushort8v*>(gth + rb + 8) = h2;
    *reinterpret_cast<ushort8v*>(gtl + rb)     = l1;
    *reinterpret_cast<ushort8v*>(gtl + rb + 8) = l2;
}

// ---------------- MFMA GEMM core (bf16x3) ----------------
// Block: 256o x 32n (full M -> LN can fuse). 4 waves, wave tile 64o x 32n.
// Frags: o-frag f=0..3, n-frag nf=0..1. A from global (L2-resident weights),
// B hi/lo double-buffered in LDS [n][72] (144B rows, conflict-free b128 reads).

#define GEMM_STEP(BUF, AH, AL)                                                   \
    {                                                                            \
        short8v bh0 = *reinterpret_cast<const short8v*>(&Bl[BUF][l15][l4 * 8]);  \
        short8v bh1 = *reinterpret_cast<const short8v*>(&Bl[BUF][16 + l15][l4 * 8]); \
        short8v bl0 = *reinterpret_cast<const short8v*>(&Bl[BUF][l15][32 + l4 * 8]); \
        short8v bl1 = *reinterpret_cast<const short8v*>(&Bl[BUF][16 + l15][32 + l4 * 8]); \
        _Pragma("unroll")                                                        \
        for (int f = 0; f < 4; f++) {                                            \
            acc[f][0] = MFMA(AH[f], bh0, acc[f][0]);                             \
            acc[f][0] = MFMA(AH[f], bl0, acc[f][0]);                             \
            acc[f][0] = MFMA(AL[f], bh0, acc[f][0]);                             \
            acc[f][1] = MFMA(AH[f], bh1, acc[f][1]);                             \
            acc[f][1] = MFMA(AH[f], bl1, acc[f][1]);                             \
            acc[f][1] = MFMA(AL[f], bh1, acc[f][1]);                             \
        }                                                                        \
    }

// K4a: x = Wp @ G + bp, LayerNorm over o, write x_ln^T hi/lo [bn][256]
__global__ __launch_bounds__(256) void k4a_proj(const unsigned short* __restrict__ wph,
                                                const unsigned short* __restrict__ wpl,
                                                const unsigned short* __restrict__ gth,
                                                const unsigned short* __restrict__ gtl,
                                                const float* __restrict__ bp,
                                                unsigned short* __restrict__ xth,
                                                unsigned short* __restrict__ xtl) {
    const int NKS = D_IN / 32;                     // 24
    int bn0 = blockIdx.x * 32;
    int t = threadIdx.x, wv = t >> 6, l = t & 63;
    int l15 = l & 15, l4 = l >> 4;

    __shared__ unsigned short Bl[2][32][72];
    __shared__ float red1[4][32], red2[4][32], mu_s[32], rs_s[32];

    int sn = t >> 3, skk = (t & 7) * 4;
    const unsigned short* gbh = gth + (size_t)(bn0 + sn) * D_IN + skk;
    const unsigned short* gbl = gtl + (size_t)(bn0 + sn) * D_IN + skk;
    const unsigned short* wa  = wph + (size_t)(wv * 64 + l15) * D_IN + l4 * 8;
    const unsigned short* wal = wpl + (size_t)(wv * 64 + l15) * D_IN + l4 * 8;

    f32x4 acc[4][2];
    #pragma unroll
    for (int f = 0; f < 4; f++)
        #pragma unroll
        for (int nf = 0; nf < 2; nf++)
            acc[f][nf] = (f32x4){0.f, 0.f, 0.f, 0.f};

    // prologue: stage chunk 0, prefetch A for step 0
    {
        ushort4 h0 = *reinterpret_cast<const ushort4*>(gbh);
        ushort4 q0 = *reinterpret_cast<const ushort4*>(gbl);
        *reinterpret_cast<ushort4*>(&Bl[0][sn][skk])      = h0;
        *reinterpret_cast<ushort4*>(&Bl[0][sn][32 + skk]) = q0;
    }
    short8v A0h[4], A0l[4], A1h[4], A1l[4];
    #pragma unroll
    for (int f = 0; f < 4; f++) {
        A0h[f] = *reinterpret_cast<const short8v*>(wa  + f * 16 * D_IN);
        A0l[f] = *reinterpret_cast<const short8v*>(wal + f * 16 * D_IN);
    }
    __syncthreads();

    for (int ks = 0; ks < NKS; ks += 2) {
        // ---- even step: consume Bl[0]/A0, prefetch ks+1 -> Bl[1]/A1
        ushort4 nh = *reinterpret_cast<const ushort4*>(gbh + (ks + 1) * 32);
        ushort4 nl = *reinterpret_cast<const ushort4*>(gbl + (ks + 1) * 32);
        #pragma unroll
        for (int f = 0; f < 4; f++) {
            A1h[f] = *reinterpret_cast<const short8v*>(wa  + f * 16 * D_IN + (ks + 1) * 32);
            A1l[f] = *reinterpret_cast<const short8v*>(wal + f * 16 * D_IN + (ks + 1) * 32);
        }
        GEMM_STEP(0, A0h, A0l)
        *reinterpret_cast<ushort4*>(&Bl[1][sn][skk])      = nh;
        *reinterpret_cast<ushort4*>(&Bl[1][sn][32 + skk]) = nl;
        __syncthreads();
        // ---- odd step: consume Bl[1]/A1, prefetch ks+2 -> Bl[0]/A0
        if (ks + 2 < NKS) {
            ushort4 mh = *reinterpret_cast<const ushort4*>(gbh + (ks + 2) * 32);
            ushort4 ml = *reinterpret_cast<const ushort4*>(gbl + (ks + 2) * 32);
            #pragma unroll
            for (int f = 0; f < 4; f++) {
                A0h[f] = *reinterpret_cast<const short8v*>(wa  + f * 16 * D_IN + (ks + 2) * 32);
                A0l[f] = *reinterpret_cast<const short8v*>(wal + f * 16 * D_IN + (ks + 2) * 32);
            }
            GEMM_STEP(1, A1h, A1l)
            *reinterpret_cast<ushort4*>(&Bl[0][sn][skk])      = mh;
            *reinterpret_cast<ushort4*>(&Bl[0][sn][32 + skk]) = ml;
            __syncthreads();
        } else {
            GEMM_STEP(1, A1h, A1l)
        }
    }

    // ---- epilogue: +bias, LayerNorm over o (256), split, store transposed
    #pragma unroll
    for (int f = 0; f < 4; f++) {
        float4 bv = *reinterpret_cast<const float4*>(bp + wv * 64 + f * 16 + l4 * 4);
        #pragma unroll
        for (int nf = 0; nf < 2; nf++) {
            acc[f][nf][0] += bv.x; acc[f][nf][1] += bv.y;
            acc[f][nf][2] += bv.z; acc[f][nf][3] += bv.w;
        }
    }
    float s1a = 0.f, s2a = 0.f, s1b = 0.f, s2b = 0.f;
    #pragma unroll
    for (int f = 0; f < 4; f++)
        #pragma unroll
        for (int r = 0; r < 4; r++) {
            float va = acc[f][0][r], vb = acc[f][1][r];
            s1a += va; s2a = fmaf(va, va, s2a);
            s1b += vb; s2b = fmaf(vb, vb, s2b);
        }
    s1a += __shfl_xor(s1a, 16); s1a += __shfl_xor(s1a, 32);
    s2a += __shfl_xor(s2a, 16); s2a += __shfl_xor(s2a, 32);
    s1b += __shfl_xor(s1b, 16); s1b += __shfl_xor(s1b, 32);
    s2b += __shfl_xor(s2b, 16); s2b += __shfl_xor(s2b, 32);
    if (l < 16) {
        red1[wv][l] = s1a; red1[wv][16 + l] = s1b;
        red2[wv][l] = s2a; red2[wv][16 + l] = s2b;
    }
    __syncthreads();
    if (t < 32) {
        float a = red1[0][t] + red1[1][t] + red1[2][t] + red1[3][t];
        float q = red2[0][t] + red2[1][t] + red2[2][t] + red2[3][t];
        float mu = a * (1.f / 256.f);
        float var = q * (1.f / 256.f) - mu * mu;
        mu_s[t] = mu;
        rs_s[t] = rsqrtf(var + 1e-5f);
    }
    __syncthreads();
    #pragma unroll
    for (int nf = 0; nf < 2; nf++) {
        float mu = mu_s[nf * 16 + l15], rs = rs_s[nf * 16 + l15];
        size_t rowb = (size_t)(bn0 + nf * 16 + l15) * 256 + wv * 64 + l4 * 4;
        #pragma unroll
        for (int f = 0; f < 4; f++) {
            ushort4 hh, ll;
            float x0 = (acc[f][nf][0] - mu) * rs;
            float x1 = (acc[f][nf][1] - mu) * rs;
            float x2 = (acc[f][nf][2] - mu) * rs;
            float x3 = (acc[f][nf][3] - mu) * rs;
            hh.x = f2bf(x0); ll.x = f2bf(x0 - bf2f(hh.x));
            hh.y = f2bf(x1); ll.y = f2bf(x1 - bf2f(hh.y));
            hh.z = f2bf(x2); ll.z = f2bf(x2 - bf2f(hh.z));
            hh.w = f2bf(x3); ll.w = f2bf(x3 - bf2f(hh.w));
            *reinterpret_cast<ushort4*>(xth + rowb + f * 16) = hh;
            *reinterpret_cast<ushort4*>(xtl + rowb + f * 16) = ll;
        }
    }
}

// K4b/c: adapter GEMMs, K=256. FINAL=0: relu -> Ht hi/lo. FINAL=1: out + loss.
template<int FINAL>
__global__ __launch_bounds__(256) void k4bc(const unsigned short* __restrict__ Wh,
                                            const unsigned short* __restrict__ Wl,
                                            const unsigned short* __restrict__ Bth,
                                            const unsigned short* __restrict__ Btl,
                                            const float* __restrict__ bias,
                                            unsigned short* __restrict__ oth,
                                            unsigned short* __restrict__ otl,
                                            const float* __restrict__ ft,
                                            float* __restrict__ out,
                                            float* __restrict__ loss) {
    const int NKS = 256 / 32;                      // 8
    int bn0 = blockIdx.x * 32;
    int t = threadIdx.x, wv = t >> 6, l = t & 63;
    int l15 = l & 15, l4 = l >> 4;

    __shared__ unsigned short Bl[2][32][72];
    __shared__ float lred[4];

    int sn = t >> 3, skk = (t & 7) * 4;
    const unsigned short* gbh = Bth + (size_t)(bn0 + sn) * 256 + skk;
    const unsigned short* gbl = Btl + (size_t)(bn0 + sn) * 256 + skk;
    const unsigned short* wa  = Wh + (size_t)(wv * 64 + l15) * 256 + l4 * 8;
    const unsigned short* wal = Wl + (size_t)(wv * 64 + l15) * 256 + l4 * 8;

    f32x4 acc[4][2];
    #pragma unroll
    for (int f = 0; f < 4; f++)
        #pragma unroll
        for (int nf = 0; nf < 2; nf++)
            acc[f][nf] = (f32x4){0.f, 0.f, 0.f, 0.f};

    {
        ushort4 h0 = *reinterpret_cast<const ushort4*>(gbh);
        ushort4 q0 = *reinterpret_cast<const ushort4*>(gbl);
        *reinterpret_cast<ushort4*>(&Bl[0][sn][skk])      = h0;
        *reinterpret_cast<ushort4*>(&Bl[0][sn][32 + skk]) = q0;
    }
    short8v A0h[4], A0l[4], A1h[4], A1l[4];
    #pragma unroll
    for (int f = 0; f < 4; f++) {
        A0h[f] = *reinterpret_cast<const short8v*>(wa  + f * 16 * 256);
        A0l[f] = *reinterpret_cast<const short8v*>(wal + f * 16 * 256);
    }
    __syncthreads();

    for (int ks = 0; ks < NKS; ks += 2) {
        ushort4 nh = *reinterpret_cast<const ushort4*>(gbh + (ks + 1) * 32);
        ushort4 nl = *reinterpret_cast<const ushort4*>(gbl + (ks + 1) * 32);
        #pragma unroll
        for (int f = 0; f < 4; f++) {
            A1h[f] = *reinterpret_cast<const short8v*>(wa  + f * 16 * 256 + (ks + 1) * 32);
            A1l[f] = *reinterpret_cast<const short8v*>(wal + f * 16 * 256 + (ks + 1) * 32);
        }
        GEMM_STEP(0, A0h, A0l)
        *reinterpret_cast<ushort4*>(&Bl[1][sn][skk])      = nh;
        *reinterpret_cast<ushort4*>(&Bl[1][sn][32 + skk]) = nl;
        __syncthreads();
        if (ks + 2 < NKS) {
            ushort4 mh = *reinterpret_cast<const ushort4*>(gbh + (ks + 2) * 32);
            ushort4 ml = *reinterpret_cast<const ushort4*>(gbl + (ks + 2) * 32);
            #pragma unroll
            for (int f = 0; f < 4; f++) {
                A0h[f] = *reinterpret_cast<const short8v*>(wa  + f * 16 * 256 + (ks + 2) * 32);
                A0l[f] = *reinterpret_cast<const short8v*>(wal + f * 16 * 256 + (ks + 2) * 32);
            }
            GEMM_STEP(1, A1h, A1l)
            *reinterpret_cast<ushort4*>(&Bl[0][sn][skk])      = mh;
            *reinterpret_cast<ushort4*>(&Bl[0][sn][32 + skk]) = ml;
            __syncthreads();
        } else {
            GEMM_STEP(1, A1h, A1l)
        }
    }

    if (FINAL == 0) {
        // relu epilogue -> Ht hi/lo (transposed [bn][256])
        #pragma unroll
        for (int f = 0; f < 4; f++) {
            float4 bv = *reinterpret_cast<const float4*>(bias + wv * 64 + f * 16 + l4 * 4);
            #pragma unroll
            for (int nf = 0; nf < 2; nf++) {
                size_t rowb = (size_t)(bn0 + nf * 16 + l15) * 256 + wv * 64 + l4 * 4;
                float x0 = fmaxf(acc[f][nf][0] + bv.x, 0.f);
                float x1 = fmaxf(acc[f][nf][1] + bv.y, 0.f);
                float x2 = fmaxf(acc[f][nf][2] + bv.z, 0.f);
                float x3 = fmaxf(acc[f][nf][3] + bv.w, 0.f);
                ushort4 hh, ll;
                hh.x = f2bf(x0); ll.x = f2bf(x0 - bf2f(hh.x));
                hh.y = f2bf(x1); ll.y = f2bf(x1 - bf2f(hh.y));
                hh.z = f2bf(x2); ll.z = f2bf(x2 - bf2f(hh.z));
                hh.w = f2bf(x3); ll.w = f2bf(x3 - bf2f(hh.w));
                *reinterpret_cast<ushort4*>(oth + rowb + f * 16) = hh;
                *reinterpret_cast<ushort4*>(otl + rowb + f * 16) = ll;
            }
        }
    } else {
        // f_student write ([b][o][n] f32) + loss partial
        int b = bn0 >> 11, nb = bn0 & 2047;
        float ls = 0.f;
        #pragma unroll
        for (int f = 0; f < 4; f++) {
            float4 bv = *reinterpret_cast<const float4*>(bias + wv * 64 + f * 16 + l4 * 4);
            #pragma unroll
            for (int nf = 0; nf < 2; nf++) {
                int n = nb + nf * 16 + l15;
                int o = wv * 64 + f * 16 + l4 * 4;
                size_t base = ((size_t)(b * 256 + o)) * NS + n;
                float v0 = acc[f][nf][0] + bv.x;
                float v1 = acc[f][nf][1] + bv.y;
                float v2 = acc[f][nf][2] + bv.z;
                float v3 = acc[f][nf][3] + bv.w;
                out[base]            = v0;
                out[base + NS]       = v1;
                out[base + 2 * NS]   = v2;
                out[base + 3 * NS]   = v3;
                float d0 = v0 - ft[base];
                float d1 = v1 - ft[base + NS];
                float d2 = v2 - ft[base + 2 * NS];
                float d3 = v3 - ft[base + 3 * NS];
                ls = fmaf(d0, d0, ls); ls = fmaf(d1, d1, ls);
                ls = fmaf(d2, d2, ls); ls = fmaf(d3, d3, ls);
            }
        }
        ls += __shfl_xor(ls, 1);  ls += __shfl_xor(ls, 2);
        ls += __shfl_xor(ls, 4);  ls += __shfl_xor(ls, 8);
        ls += __shfl_xor(ls, 16); ls += __shfl_xor(ls, 32);
        if (l == 0) lred[wv] = ls;
        __syncthreads();
        if (t == 0)
            atomicAdd(loss, (lred[0] + lred[1] + lred[2] + lred[3]) * (1.f / 4194304.f));
    }
}

extern "C" void kernel_launch(void* const* d_in, const int* in_sizes, int n_in,
                              void* d_out, int out_size, void* d_ws, size_t ws_size,
                              hipStream_t stream) {
    const float* pc   = (const float*)d_in[0];
    const float* seed = (const float*)d_in[1];
    const float* pts  = (const float*)d_in[2];
    const float* feat = (const float*)d_in[3];
    const float* ft   = (const float*)d_in[4];
    const float* Wp   = (const float*)d_in[5];
    const float* bp   = (const float*)d_in[6];
    const float* Wa1  = (const float*)d_in[7];
    const float* b1v  = (const float*)d_in[8];
    const float* Wa2  = (const float*)d_in[9];
    const float* b2v  = (const float*)d_in[10];

    float* out = (float*)d_out;                        // [8][256][2048] + 1 loss
    float* ws  = (float*)d_ws;
    float*          stats = ws + OFF_STATS;
    unsigned short* wph = (unsigned short*)(ws + OFF_WPH);
    unsigned short* wpl = (unsigned short*)(ws + OFF_WPL);
    unsigned short* w1h = (unsigned short*)(ws + OFF_W1H);
    unsigned short* w1l = (unsigned short*)(ws + OFF_W1L);
    unsigned short* w2h = (unsigned short*)(ws + OFF_W2H);
    unsigned short* w2l = (unsigned short*)(ws + OFF_W2L);
    float*          pd  = ws + OFF_PD;
    int*            pi  = (int*)(ws + OFF_PI);
    int*            idx = (int*)(ws + OFF_IDX);
    unsigned short* gth = (unsigned short*)(ws + OFF_GTH);
    unsigned short* gtl = (unsigned short*)(ws + OFF_GTL);
    float*          G   = ws + OFF_G;
    unsigned short* xth = (unsigned short*)(ws + OFF_XTH);
    unsigned short* xtl = (unsigned short*)(ws + OFF_XTL);
    unsigned short* hth = (unsigned short*)(ws + OFF_HTH);
    unsigned short* htl = (unsigned short*)(ws + OFF_HTL);
    float* loss_slot = out + (size_t)NB * C_OUT * NS;  // index 4194304

    k0_prep<<<1280, 256, 0, stream>>>(Wp, Wa1, Wa2, wph, wpl, w1h, w1l, w2h, w2l, loss_slot);
    k1_stats<<<NB, 1024, 0, stream>>>(pc, stats);
    k2_nn<<<dim3(NS / (256 * SPT), KSPLIT, NB), 256, 0, stream>>>(seed, pts, stats, pd, pi);
    k2b_merge<<<(NB * NS) / 256, 256, 0, stream>>>(pd, pi, idx);
    k3_gather<<<NB * D_IN, 256, 0, stream>>>(feat, idx, G);
    k3b_tr<<<dim3(D_IN / 64, (NB * NS) / 64), 256, 0, stream>>>(G, gth, gtl);
    k4a_proj<<<(NB * NS) / 32, 256, 0, stream>>>(wph, wpl, gth, gtl, bp, xth, xtl);
    k4bc<0><<<(NB * NS) / 32, 256, 0, stream>>>(w1h, w1l, xth, xtl, b1v,
                                                hth, htl, nullptr, nullptr, nullptr);
    k4bc<1><<<(NB * NS) / 32, 256, 0, stream>>>(w2h, w2l, hth, htl, b2v,
                                                nullptr, nullptr, ft, out, loss_slot);
}

// Round 5
// 764.146 us; speedup vs baseline: 1.4238x; 1.0774x over previous
//
#include <hip/hip_runtime.h>
#include <hip/hip_bf16.h>
#include <float.h>
#include <math.h>

// Problem shapes (fixed per setup_inputs)
#define NB     8
#define N_PC   20000
#define NS     2048
#define KPTS   16384
#define D_IN   768
#define C_OUT  256
#define KSPLIT 32
#define SPT    4

typedef __attribute__((ext_vector_type(8))) short  short8v;   // 8 bf16 = 4 VGPR (MFMA A/B frag)
typedef __attribute__((ext_vector_type(8))) unsigned short ushort8v;
typedef __attribute__((ext_vector_type(4))) float  f32x4;     // MFMA C/D frag

#define MFMA(a,b,c) __builtin_amdgcn_mfma_f32_16x16x32_bf16((a),(b),(c),0,0,0)

// ---------------- ws layout (float units) ----------------
#define OFF_STATS 0
#define OFF_WPH   32
#define OFF_WPL   (OFF_WPH + 98304)      // 256*768 ushort = 98304 f
#define OFF_W1H   (OFF_WPL + 98304)
#define OFF_W1L   (OFF_W1H + 32768)      // 256*256 ushort = 32768 f
#define OFF_W2H   (OFF_W1L + 32768)
#define OFF_W2L   (OFF_W2H + 32768)
#define OFF_PD    (OFF_W2L + 32768)
#define OFF_PI    (OFF_PD + NB*KSPLIT*NS)
#define OFF_IDX   (OFF_PI + NB*KSPLIT*NS)
#define OFF_GTH   (OFF_IDX + NB*NS)      // 16384*768 ushort = 6291456 f
#define OFF_GTL   (OFF_GTH + 6291456)
#define OFF_G     (OFF_GTL + 6291456)    // 12582912 f ; reused for Xt/Ht after k3b
#define OFF_XTH   OFF_G                  // 16384*256 ushort = 2097152 f
#define OFF_XTL   (OFF_XTH + 2097152)
#define OFF_HTH   (OFF_XTL + 2097152)
#define OFF_HTL   (OFF_HTH + 2097152)

// ---- bf16 split helpers (RNE, matches __float2bfloat16) ----
__device__ __forceinline__ unsigned short f2bf(float x) {
    unsigned u = __float_as_uint(x);
    unsigned r = (u + 0x7FFFu + ((u >> 16) & 1u)) >> 16;
    return (unsigned short)r;
}
__device__ __forceinline__ float bf2f(unsigned short b) {
    return __uint_as_float(((unsigned)b) << 16);
}

// K0: weights -> hi/lo bf16 (layout preserved: [o][k] row-major = MFMA A layout); zero loss
__global__ void k0_prep(const float* __restrict__ Wp, const float* __restrict__ W1,
                        const float* __restrict__ W2,
                        unsigned short* __restrict__ wph, unsigned short* __restrict__ wpl,
                        unsigned short* __restrict__ w1h, unsigned short* __restrict__ w1l,
                        unsigned short* __restrict__ w2h, unsigned short* __restrict__ w2l,
                        float* __restrict__ loss_slot) {
    int t = blockIdx.x * 256 + threadIdx.x;
    if (t == 0) *loss_slot = 0.f;
    if (t < 196608) {
        float x = Wp[t]; unsigned short h = f2bf(x);
        wph[t] = h; wpl[t] = f2bf(x - bf2f(h));
    } else if (t < 262144) {
        int i = t - 196608;
        float x = W1[i]; unsigned short h = f2bf(x);
        w1h[i] = h; w1l[i] = f2bf(x - bf2f(h));
    } else if (t < 327680) {
        int i = t - 262144;
        float x = W2[i]; unsigned short h = f2bf(x);
        w2h[i] = h; w2l[i] = f2bf(x - bf2f(h));
    }
}

// K1: per-batch centroid + max-radius scale (1024 threads)
__global__ void k1_stats(const float* __restrict__ pc, float* __restrict__ stats) {
    int b = blockIdx.x, t = threadIdx.x;
    __shared__ float rx[1024], ry[1024], rz[1024];
    __shared__ float c3[3];
    const float* p = pc + (size_t)b * N_PC * 3;
    float sx = 0.f, sy = 0.f, sz = 0.f;
    for (int i = t; i < N_PC; i += 1024) {
        sx += p[3 * i]; sy += p[3 * i + 1]; sz += p[3 * i + 2];
    }
    rx[t] = sx; ry[t] = sy; rz[t] = sz;
    __syncthreads();
    for (int s = 512; s > 0; s >>= 1) {
        if (t < s) { rx[t] += rx[t + s]; ry[t] += ry[t + s]; rz[t] += rz[t + s]; }
        __syncthreads();
    }
    if (t == 0) {
        c3[0] = rx[0] / 20000.f; c3[1] = ry[0] / 20000.f; c3[2] = rz[0] / 20000.f;
    }
    __syncthreads();
    float cx = c3[0], cy = c3[1], cz = c3[2];
    float mx = 0.f;
    for (int i = t; i < N_PC; i += 1024) {
        float dx = p[3 * i] - cx, dy = p[3 * i + 1] - cy, dz = p[3 * i + 2] - cz;
        mx = fmaxf(mx, dx * dx + dy * dy + dz * dz);
    }
    rx[t] = mx;
    __syncthreads();
    for (int s = 512; s > 0; s >>= 1) {
        if (t < s) rx[t] = fmaxf(rx[t], rx[t + s]);
        __syncthreads();
    }
    if (t == 0) {
        stats[b * 4 + 0] = cx; stats[b * 4 + 1] = cy; stats[b * 4 + 2] = cz;
        stats[b * 4 + 3] = sqrtf(rx[0]);
    }
}

// K2: 1-NN partial argmin, KSPLIT=32 -> 512 blocks (2/CU)
__global__ void k2_nn(const float* __restrict__ seed, const float* __restrict__ pts,
                      const float* __restrict__ stats,
                      float* __restrict__ pd, int* __restrict__ pi) {
    int tile = blockIdx.x, split = blockIdx.y, b = blockIdx.z, t = threadIdx.x;
    float cx = stats[b * 4], cy = stats[b * 4 + 1], cz = stats[b * 4 + 2], sc = stats[b * 4 + 3];

    float sx[SPT], sy[SPT], sz[SPT], ssv[SPT];
    float best[SPT];
    int   bi[SPT];
    #pragma unroll
    for (int i = 0; i < SPT; i++) {
        int n = tile * (256 * SPT) + i * 256 + t;
        const float* s3 = seed + ((size_t)b * NS + n) * 3;
        sx[i] = (s3[0] - cx) / sc;
        sy[i] = (s3[1] - cy) / sc;
        sz[i] = (s3[2] - cz) / sc;
        ssv[i] = fmaf(sz[i], sz[i], fmaf(sy[i], sy[i], sx[i] * sx[i]));
        best[i] = FLT_MAX;
        bi[i] = 0;
    }

    __shared__ float4 lp[256];
    const int kbeg = split * (KPTS / KSPLIT);          // 512 points per split
    for (int kc = kbeg; kc < kbeg + KPTS / KSPLIT; kc += 256) {
        const float* p3 = pts + ((size_t)b * KPTS + kc + t) * 3;
        float px = (p3[0] - cx) / sc, py = (p3[1] - cy) / sc, pz = (p3[2] - cz) / sc;
        lp[t] = make_float4(px, py, pz, fmaf(pz, pz, fmaf(py, py, px * px)));
        __syncthreads();
        #pragma unroll 4
        for (int j = 0; j < 256; j++) {
            float4 q = lp[j];
            int cand = kc + j;
            #pragma unroll
            for (int i = 0; i < SPT; i++) {
                float dot = fmaf(sz[i], q.z, fmaf(sy[i], q.y, sx[i] * q.x));
                float d = (ssv[i] + q.w) - 2.f * dot;
                bool m = d < best[i];
                best[i] = m ? d : best[i];
                bi[i]   = m ? cand : bi[i];
            }
        }
        __syncthreads();
    }
    #pragma unroll
    for (int i = 0; i < SPT; i++) {
        int n = tile * (256 * SPT) + i * 256 + t;
        pd[((size_t)b * KSPLIT + split) * NS + n] = best[i];
        pi[((size_t)b * KSPLIT + split) * NS + n] = bi[i];
    }
}

// K2b: merge K-split partials (split ascending => lowest-k wins ties via strict <)
__global__ void k2b_merge(const float* __restrict__ pd, const int* __restrict__ pi,
                          int* __restrict__ idx) {
    int g = blockIdx.x * 256 + threadIdx.x;
    int b = g >> 11, n = g & 2047;
    float best = FLT_MAX;
    int bi = 0;
    for (int s = 0; s < KSPLIT; s++) {
        float d = pd[((size_t)b * KSPLIT + s) * NS + n];
        int i = pi[((size_t)b * KSPLIT + s) * NS + n];
        if (d < best) { best = d; bi = i; }
    }
    idx[b * NS + n] = bi;
}

// K3: gather G[b][d][n] = feat[b][d][idx[b][n]].
// Round-3 fix (unmeasured, resubmitted): the scattered 4B global gather
// thrashed L2 (~16 MB of rows in flight per XCD vs 4 MB L2) -> ~800 MB
// effective fetch ~300 us. Now: stage the whole 64 KB row in LDS with
// coalesced float4 streaming reads, gather from LDS. Feat read = 402 MB
// sequential floor; values bit-identical.
__global__ __launch_bounds__(256) void k3_gather(const float* __restrict__ feat,
                                                 const int* __restrict__ idx,
                                                 float* __restrict__ G) {
    int bd = blockIdx.x;
    int b = bd / D_IN;
    __shared__ float row[KPTS];                       // 64 KB -> 2 blocks/CU
    const float4* frow4 = reinterpret_cast<const float4*>(feat + (size_t)bd * KPTS);
    float4* row4 = reinterpret_cast<float4*>(row);
    #pragma unroll 4
    for (int i = threadIdx.x; i < KPTS / 4; i += 256)
        row4[i] = frow4[i];
    __syncthreads();
    const int* ib = idx + b * NS;
    float* grow = G + (size_t)bd * NS;
    #pragma unroll 2
    for (int n = threadIdx.x; n < NS; n += 256)
        grow[n] = row[ib[n]];
}

// K3b: transpose+split G[b][d][n] f32 -> Gt_hi/Gt_lo [bn][768] bf16 (k-contiguous B layout)
__global__ __launch_bounds__(256) void k3b_tr(const float* __restrict__ G,
                                              unsigned short* __restrict__ gth,
                                              unsigned short* __restrict__ gtl) {
    int d0 = blockIdx.x * 64, bn0 = blockIdx.y * 64;
    int b = bn0 >> 11, nb = bn0 & 2047;
    __shared__ float ld[64][65];
    int t = threadIdx.x;
    int rr = t >> 2, cc = (t & 3) * 16;
    const float* gp = G + ((size_t)(b * D_IN + d0 + rr)) * NS + nb + cc;
    #pragma unroll
    for (int i = 0; i < 4; i++) {
        float4 v = *reinterpret_cast<const float4*>(gp + i * 4);
        ld[rr][cc + i * 4 + 0] = v.x; ld[rr][cc + i * 4 + 1] = v.y;
        ld[rr][cc + i * 4 + 2] = v.z; ld[rr][cc + i * 4 + 3] = v.w;
    }
    __syncthreads();
    int nl = t >> 2, dg = (t & 3) * 16;
    ushort8v h1, h2, l1, l2;
    #pragma unroll
    for (int i = 0; i < 8; i++) {
        float v = ld[dg + i][nl];
        unsigned short h = f2bf(v);
        h1[i] = h; l1[i] = f2bf(v - bf2f(h));
    }
    #pragma unroll
    for (int i = 0; i < 8; i++) {
        float v = ld[dg + 8 + i][nl];
        unsigned short h = f2bf(v);
        h2[i] = h; l2[i] = f2bf(v - bf2f(h));
    }
    size_t rb = ((size_t)(bn0 + nl)) * D_IN + d0 + dg;
    *reinterpret_cast<ushort8v*>(gth + rb)     = h1;
    *reinterpret_cast<ushort8v*>(gth + rb + 8) = h2;
    *reinterpret_cast<ushort8v*>(gtl + rb)     = l1;
    *reinterpret_cast<ushort8v*>(gtl + rb + 8) = l2;
}

// ---------------- MFMA GEMM core (bf16x3) ----------------
// Block: 256o x 32n (full M -> LN can fuse). 4 waves, wave tile 64o x 32n.
// Frags: o-frag f=0..3, n-frag nf=0..1. A from global (L2-resident weights),
// B hi/lo double-buffered in LDS [n][72] (144B rows, conflict-free b128 reads).

#define GEMM_STEP(BUF, AH, AL)                                                   \
    {                                                                            \
        short8v bh0 = *reinterpret_cast<const short8v*>(&Bl[BUF][l15][l4 * 8]);  \
        short8v bh1 = *reinterpret_cast<const short8v*>(&Bl[BUF][16 + l15][l4 * 8]); \
        short8v bl0 = *reinterpret_cast<const short8v*>(&Bl[BUF][l15][32 + l4 * 8]); \
        short8v bl1 = *reinterpret_cast<const short8v*>(&Bl[BUF][16 + l15][32 + l4 * 8]); \
        _Pragma("unroll")                                                        \
        for (int f = 0; f < 4; f++) {                                            \
            acc[f][0] = MFMA(AH[f], bh0, acc[f][0]);                             \
            acc[f][0] = MFMA(AH[f], bl0, acc[f][0]);                             \
            acc[f][0] = MFMA(AL[f], bh0, acc[f][0]);                             \
            acc[f][1] = MFMA(AH[f], bh1, acc[f][1]);                             \
            acc[f][1] = MFMA(AH[f], bl1, acc[f][1]);                             \
            acc[f][1] = MFMA(AL[f], bh1, acc[f][1]);                             \
        }                                                                        \
    }

// K4a: x = Wp @ G + bp, LayerNorm over o, write x_ln^T hi/lo [bn][256]
__global__ __launch_bounds__(256) void k4a_proj(const unsigned short* __restrict__ wph,
                                                const unsigned short* __restrict__ wpl,
                                                const unsigned short* __restrict__ gth,
                                                const unsigned short* __restrict__ gtl,
                                                const float* __restrict__ bp,
                                                unsigned short* __restrict__ xth,
                                                unsigned short* __restrict__ xtl) {
    const int NKS = D_IN / 32;                     // 24
    int bn0 = blockIdx.x * 32;
    int t = threadIdx.x, wv = t >> 6, l = t & 63;
    int l15 = l & 15, l4 = l >> 4;

    __shared__ unsigned short Bl[2][32][72];
    __shared__ float red1[4][32], red2[4][32], mu_s[32], rs_s[32];

    int sn = t >> 3, skk = (t & 7) * 4;
    const unsigned short* gbh = gth + (size_t)(bn0 + sn) * D_IN + skk;
    const unsigned short* gbl = gtl + (size_t)(bn0 + sn) * D_IN + skk;
    const unsigned short* wa  = wph + (size_t)(wv * 64 + l15) * D_IN + l4 * 8;
    const unsigned short* wal = wpl + (size_t)(wv * 64 + l15) * D_IN + l4 * 8;

    f32x4 acc[4][2];
    #pragma unroll
    for (int f = 0; f < 4; f++)
        #pragma unroll
        for (int nf = 0; nf < 2; nf++)
            acc[f][nf] = (f32x4){0.f, 0.f, 0.f, 0.f};

    // prologue: stage chunk 0, prefetch A for step 0
    {
        ushort4 h0 = *reinterpret_cast<const ushort4*>(gbh);
        ushort4 q0 = *reinterpret_cast<const ushort4*>(gbl);
        *reinterpret_cast<ushort4*>(&Bl[0][sn][skk])      = h0;
        *reinterpret_cast<ushort4*>(&Bl[0][sn][32 + skk]) = q0;
    }
    short8v A0h[4], A0l[4], A1h[4], A1l[4];
    #pragma unroll
    for (int f = 0; f < 4; f++) {
        A0h[f] = *reinterpret_cast<const short8v*>(wa  + f * 16 * D_IN);
        A0l[f] = *reinterpret_cast<const short8v*>(wal + f * 16 * D_IN);
    }
    __syncthreads();

    for (int ks = 0; ks < NKS; ks += 2) {
        // ---- even step: consume Bl[0]/A0, prefetch ks+1 -> Bl[1]/A1
        ushort4 nh = *reinterpret_cast<const ushort4*>(gbh + (ks + 1) * 32);
        ushort4 nl = *reinterpret_cast<const ushort4*>(gbl + (ks + 1) * 32);
        #pragma unroll
        for (int f = 0; f < 4; f++) {
            A1h[f] = *reinterpret_cast<const short8v*>(wa  + f * 16 * D_IN + (ks + 1) * 32);
            A1l[f] = *reinterpret_cast<const short8v*>(wal + f * 16 * D_IN + (ks + 1) * 32);
        }
        GEMM_STEP(0, A0h, A0l)
        *reinterpret_cast<ushort4*>(&Bl[1][sn][skk])      = nh;
        *reinterpret_cast<ushort4*>(&Bl[1][sn][32 + skk]) = nl;
        __syncthreads();
        // ---- odd step: consume Bl[1]/A1, prefetch ks+2 -> Bl[0]/A0
        if (ks + 2 < NKS) {
            ushort4 mh = *reinterpret_cast<const ushort4*>(gbh + (ks + 2) * 32);
            ushort4 ml = *reinterpret_cast<const ushort4*>(gbl + (ks + 2) * 32);
            #pragma unroll
            for (int f = 0; f < 4; f++) {
                A0h[f] = *reinterpret_cast<const short8v*>(wa  + f * 16 * D_IN + (ks + 2) * 32);
                A0l[f] = *reinterpret_cast<const short8v*>(wal + f * 16 * D_IN + (ks + 2) * 32);
            }
            GEMM_STEP(1, A1h, A1l)
            *reinterpret_cast<ushort4*>(&Bl[0][sn][skk])      = mh;
            *reinterpret_cast<ushort4*>(&Bl[0][sn][32 + skk]) = ml;
            __syncthreads();
        } else {
            GEMM_STEP(1, A1h, A1l)
        }
    }

    // ---- epilogue: +bias, LayerNorm over o (256), split, store transposed
    #pragma unroll
    for (int f = 0; f < 4; f++) {
        float4 bv = *reinterpret_cast<const float4*>(bp + wv * 64 + f * 16 + l4 * 4);
        #pragma unroll
        for (int nf = 0; nf < 2; nf++) {
            acc[f][nf][0] += bv.x; acc[f][nf][1] += bv.y;
            acc[f][nf][2] += bv.z; acc[f][nf][3] += bv.w;
        }
    }
    float s1a = 0.f, s2a = 0.f, s1b = 0.f, s2b = 0.f;
    #pragma unroll
    for (int f = 0; f < 4; f++)
        #pragma unroll
        for (int r = 0; r < 4; r++) {
            float va = acc[f][0][r], vb = acc[f][1][r];
            s1a += va; s2a = fmaf(va, va, s2a);
            s1b += vb; s2b = fmaf(vb, vb, s2b);
        }
    s1a += __shfl_xor(s1a, 16); s1a += __shfl_xor(s1a, 32);
    s2a += __shfl_xor(s2a, 16); s2a += __shfl_xor(s2a, 32);
    s1b += __shfl_xor(s1b, 16); s1b += __shfl_xor(s1b, 32);
    s2b += __shfl_xor(s2b, 16); s2b += __shfl_xor(s2b, 32);
    if (l < 16) {
        red1[wv][l] = s1a; red1[wv][16 + l] = s1b;
        red2[wv][l] = s2a; red2[wv][16 + l] = s2b;
    }
    __syncthreads();
    if (t < 32) {
        float a = red1[0][t] + red1[1][t] + red1[2][t] + red1[3][t];
        float q = red2[0][t] + red2[1][t] + red2[2][t] + red2[3][t];
        float mu = a * (1.f / 256.f);
        float var = q * (1.f / 256.f) - mu * mu;
        mu_s[t] = mu;
        rs_s[t] = rsqrtf(var + 1e-5f);
    }
    __syncthreads();
    #pragma unroll
    for (int nf = 0; nf < 2; nf++) {
        float mu = mu_s[nf * 16 + l15], rs = rs_s[nf * 16 + l15];
        size_t rowb = (size_t)(bn0 + nf * 16 + l15) * 256 + wv * 64 + l4 * 4;
        #pragma unroll
        for (int f = 0; f < 4; f++) {
            ushort4 hh, ll;
            float x0 = (acc[f][nf][0] - mu) * rs;
            float x1 = (acc[f][nf][1] - mu) * rs;
            float x2 = (acc[f][nf][2] - mu) * rs;
            float x3 = (acc[f][nf][3] - mu) * rs;
            hh.x = f2bf(x0); ll.x = f2bf(x0 - bf2f(hh.x));
            hh.y = f2bf(x1); ll.y = f2bf(x1 - bf2f(hh.y));
            hh.z = f2bf(x2); ll.z = f2bf(x2 - bf2f(hh.z));
            hh.w = f2bf(x3); ll.w = f2bf(x3 - bf2f(hh.w));
            *reinterpret_cast<ushort4*>(xth + rowb + f * 16) = hh;
            *reinterpret_cast<ushort4*>(xtl + rowb + f * 16) = ll;
        }
    }
}

// K4b/c: adapter GEMMs, K=256. FINAL=0: relu -> Ht hi/lo. FINAL=1: out + loss.
template<int FINAL>
__global__ __launch_bounds__(256) void k4bc(const unsigned short* __restrict__ Wh,
                                            const unsigned short* __restrict__ Wl,
                                            const unsigned short* __restrict__ Bth,
                                            const unsigned short* __restrict__ Btl,
                                            const float* __restrict__ bias,
                                            unsigned short* __restrict__ oth,
                                            unsigned short* __restrict__ otl,
                                            const float* __restrict__ ft,
                                            float* __restrict__ out,
                                            float* __restrict__ loss) {
    const int NKS = 256 / 32;                      // 8
    int bn0 = blockIdx.x * 32;
    int t = threadIdx.x, wv = t >> 6, l = t & 63;
    int l15 = l & 15, l4 = l >> 4;

    __shared__ unsigned short Bl[2][32][72];
    __shared__ float lred[4];

    int sn = t >> 3, skk = (t & 7) * 4;
    const unsigned short* gbh = Bth + (size_t)(bn0 + sn) * 256 + skk;
    const unsigned short* gbl = Btl + (size_t)(bn0 + sn) * 256 + skk;
    const unsigned short* wa  = Wh + (size_t)(wv * 64 + l15) * 256 + l4 * 8;
    const unsigned short* wal = Wl + (size_t)(wv * 64 + l15) * 256 + l4 * 8;

    f32x4 acc[4][2];
    #pragma unroll
    for (int f = 0; f < 4; f++)
        #pragma unroll
        for (int nf = 0; nf < 2; nf++)
            acc[f][nf] = (f32x4){0.f, 0.f, 0.f, 0.f};

    {
        ushort4 h0 = *reinterpret_cast<const ushort4*>(gbh);
        ushort4 q0 = *reinterpret_cast<const ushort4*>(gbl);
        *reinterpret_cast<ushort4*>(&Bl[0][sn][skk])      = h0;
        *reinterpret_cast<ushort4*>(&Bl[0][sn][32 + skk]) = q0;
    }
    short8v A0h[4], A0l[4], A1h[4], A1l[4];
    #pragma unroll
    for (int f = 0; f < 4; f++) {
        A0h[f] = *reinterpret_cast<const short8v*>(wa  + f * 16 * 256);
        A0l[f] = *reinterpret_cast<const short8v*>(wal + f * 16 * 256);
    }
    __syncthreads();

    for (int ks = 0; ks < NKS; ks += 2) {
        ushort4 nh = *reinterpret_cast<const ushort4*>(gbh + (ks + 1) * 32);
        ushort4 nl = *reinterpret_cast<const ushort4*>(gbl + (ks + 1) * 32);
        #pragma unroll
        for (int f = 0; f < 4; f++) {
            A1h[f] = *reinterpret_cast<const short8v*>(wa  + f * 16 * 256 + (ks + 1) * 32);
            A1l[f] = *reinterpret_cast<const short8v*>(wal + f * 16 * 256 + (ks + 1) * 32);
        }
        GEMM_STEP(0, A0h, A0l)
        *reinterpret_cast<ushort4*>(&Bl[1][sn][skk])      = nh;
        *reinterpret_cast<ushort4*>(&Bl[1][sn][32 + skk]) = nl;
        __syncthreads();
        if (ks + 2 < NKS) {
            ushort4 mh = *reinterpret_cast<const ushort4*>(gbh + (ks + 2) * 32);
            ushort4 ml = *reinterpret_cast<const ushort4*>(gbl + (ks + 2) * 32);
            #pragma unroll
            for (int f = 0; f < 4; f++) {
                A0h[f] = *reinterpret_cast<const short8v*>(wa  + f * 16 * 256 + (ks + 2) * 32);
                A0l[f] = *reinterpret_cast<const short8v*>(wal + f * 16 * 256 + (ks + 2) * 32);
            }
            GEMM_STEP(1, A1h, A1l)
            *reinterpret_cast<ushort4*>(&Bl[0][sn][skk])      = mh;
            *reinterpret_cast<ushort4*>(&Bl[0][sn][32 + skk]) = ml;
            __syncthreads();
        } else {
            GEMM_STEP(1, A1h, A1l)
        }
    }

    if (FINAL == 0) {
        // relu epilogue -> Ht hi/lo (transposed [bn][256])
        #pragma unroll
        for (int f = 0; f < 4; f++) {
            float4 bv = *reinterpret_cast<const float4*>(bias + wv * 64 + f * 16 + l4 * 4);
            #pragma unroll
            for (int nf = 0; nf < 2; nf++) {
                size_t rowb = (size_t)(bn0 + nf * 16 + l15) * 256 + wv * 64 + l4 * 4;
                float x0 = fmaxf(acc[f][nf][0] + bv.x, 0.f);
                float x1 = fmaxf(acc[f][nf][1] + bv.y, 0.f);
                float x2 = fmaxf(acc[f][nf][2] + bv.z, 0.f);
                float x3 = fmaxf(acc[f][nf][3] + bv.w, 0.f);
                ushort4 hh, ll;
                hh.x = f2bf(x0); ll.x = f2bf(x0 - bf2f(hh.x));
                hh.y = f2bf(x1); ll.y = f2bf(x1 - bf2f(hh.y));
                hh.z = f2bf(x2); ll.z = f2bf(x2 - bf2f(hh.z));
                hh.w = f2bf(x3); ll.w = f2bf(x3 - bf2f(hh.w));
                *reinterpret_cast<ushort4*>(oth + rowb + f * 16) = hh;
                *reinterpret_cast<ushort4*>(otl + rowb + f * 16) = ll;
            }
        }
    } else {
        // f_student write ([b][o][n] f32) + loss partial
        int b = bn0 >> 11, nb = bn0 & 2047;
        float ls = 0.f;
        #pragma unroll
        for (int f = 0; f < 4; f++) {
            float4 bv = *reinterpret_cast<const float4*>(bias + wv * 64 + f * 16 + l4 * 4);
            #pragma unroll
            for (int nf = 0; nf < 2; nf++) {
                int n = nb + nf * 16 + l15;
                int o = wv * 64 + f * 16 + l4 * 4;
                size_t base = ((size_t)(b * 256 + o)) * NS + n;
                float v0 = acc[f][nf][0] + bv.x;
                float v1 = acc[f][nf][1] + bv.y;
                float v2 = acc[f][nf][2] + bv.z;
                float v3 = acc[f][nf][3] + bv.w;
                out[base]            = v0;
                out[base + NS]       = v1;
                out[base + 2 * NS]   = v2;
                out[base + 3 * NS]   = v3;
                float d0 = v0 - ft[base];
                float d1 = v1 - ft[base + NS];
                float d2 = v2 - ft[base + 2 * NS];
                float d3 = v3 - ft[base + 3 * NS];
                ls = fmaf(d0, d0, ls); ls = fmaf(d1, d1, ls);
                ls = fmaf(d2, d2, ls); ls = fmaf(d3, d3, ls);
            }
        }
        ls += __shfl_xor(ls, 1);  ls += __shfl_xor(ls, 2);
        ls += __shfl_xor(ls, 4);  ls += __shfl_xor(ls, 8);
        ls += __shfl_xor(ls, 16); ls += __shfl_xor(ls, 32);
        if (l == 0) lred[wv] = ls;
        __syncthreads();
        if (t == 0)
            atomicAdd(loss, (lred[0] + lred[1] + lred[2] + lred[3]) * (1.f / 4194304.f));
    }
}

extern "C" void kernel_launch(void* const* d_in, const int* in_sizes, int n_in,
                              void* d_out, int out_size, void* d_ws, size_t ws_size,
                              hipStream_t stream) {
    const float* pc   = (const float*)d_in[0];
    const float* seed = (const float*)d_in[1];
    const float* pts  = (const float*)d_in[2];
    const float* feat = (const float*)d_in[3];
    const float* ft   = (const float*)d_in[4];
    const float* Wp   = (const float*)d_in[5];
    const float* bp   = (const float*)d_in[6];
    const float* Wa1  = (const float*)d_in[7];
    const float* b1v  = (const float*)d_in[8];
    const float* Wa2  = (const float*)d_in[9];
    const float* b2v  = (const float*)d_in[10];

    float* out = (float*)d_out;                        // [8][256][2048] + 1 loss
    float* ws  = (float*)d_ws;
    float*          stats = ws + OFF_STATS;
    unsigned short* wph = (unsigned short*)(ws + OFF_WPH);
    unsigned short* wpl = (unsigned short*)(ws + OFF_WPL);
    unsigned short* w1h = (unsigned short*)(ws + OFF_W1H);
    unsigned short* w1l = (unsigned short*)(ws + OFF_W1L);
    unsigned short* w2h = (unsigned short*)(ws + OFF_W2H);
    unsigned short* w2l = (unsigned short*)(ws + OFF_W2L);
    float*          pd  = ws + OFF_PD;
    int*            pi  = (int*)(ws + OFF_PI);
    int*            idx = (int*)(ws + OFF_IDX);
    unsigned short* gth = (unsigned short*)(ws + OFF_GTH);
    unsigned short* gtl = (unsigned short*)(ws + OFF_GTL);
    float*          G   = ws + OFF_G;
    unsigned short* xth = (unsigned short*)(ws + OFF_XTH);
    unsigned short* xtl = (unsigned short*)(ws + OFF_XTL);
    unsigned short* hth = (unsigned short*)(ws + OFF_HTH);
    unsigned short* htl = (unsigned short*)(ws + OFF_HTL);
    float* loss_slot = out + (size_t)NB * C_OUT * NS;  // index 4194304

    k0_prep<<<1280, 256, 0, stream>>>(Wp, Wa1, Wa2, wph, wpl, w1h, w1l, w2h, w2l, loss_slot);
    k1_stats<<<NB, 1024, 0, stream>>>(pc, stats);
    k2_nn<<<dim3(NS / (256 * SPT), KSPLIT, NB), 256, 0, stream>>>(seed, pts, stats, pd, pi);
    k2b_merge<<<(NB * NS) / 256, 256, 0, stream>>>(pd, pi, idx);
    k3_gather<<<NB * D_IN, 256, 0, stream>>>(feat, idx, G);
    k3b_tr<<<dim3(D_IN / 64, (NB * NS) / 64), 256, 0, stream>>>(G, gth, gtl);
    k4a_proj<<<(NB * NS) / 32, 256, 0, stream>>>(wph, wpl, gth, gtl, bp, xth, xtl);
    k4bc<0><<<(NB * NS) / 32, 256, 0, stream>>>(w1h, w1l, xth, xtl, b1v,
                                                hth, htl, nullptr, nullptr, nullptr);
    k4bc<1><<<(NB * NS) / 32, 256, 0, stream>>>(w2h, w2l, hth, htl, b2v,
                                                nullptr, nullptr, ft, out, loss_slot);
}